// Round 1
// baseline (1697.094 us; speedup 1.0000x reference)
//
#include <hip/hip_runtime.h>

typedef unsigned short u16;
typedef __bf16 bf16x8 __attribute__((ext_vector_type(8)));
typedef float f32x4 __attribute__((ext_vector_type(4)));

#define LOG2E 1.44269504089f

// ---------- bf16 helpers (manual RNE; inputs are finite) ----------
__device__ __forceinline__ u16 f2b(float f) {
  unsigned u = __builtin_bit_cast(unsigned, f);
  u += 0x7fffu + ((u >> 16) & 1u);
  return (u16)(u >> 16);
}
__device__ __forceinline__ float b2f(u16 h) {
  unsigned u = ((unsigned)h) << 16;
  return __builtin_bit_cast(float, u);
}
__device__ __forceinline__ f32x4 mfma_bf16(bf16x8 a, bf16x8 b, f32x4 c) {
  return __builtin_amdgcn_mfma_f32_16x16x32_bf16(a, b, c, 0, 0, 0);
}
// async global->LDS, 16B per lane; LDS dest must be wave-uniform base + lane*16
__device__ __forceinline__ void gload16(const void* g, void* l) {
  __builtin_amdgcn_global_load_lds(
      (const __attribute__((address_space(1))) unsigned int*)g,
      (__attribute__((address_space(3))) unsigned int*)l, 16, 0, 0);
}

// ---------- split x (fp32 -> hi/lo bf16), 4 elems/thread ----------
__global__ __launch_bounds__(256) void split_kernel(const float* __restrict__ x,
                                                    u16* __restrict__ xh,
                                                    u16* __restrict__ xl) {
  int i = blockIdx.x * 256 + threadIdx.x;
  float4 v = ((const float4*)x)[i];
  ushort4 h, l;
  h.x = f2b(v.x); l.x = f2b(v.x - b2f(h.x));
  h.y = f2b(v.y); l.y = f2b(v.y - b2f(h.y));
  h.z = f2b(v.z); l.z = f2b(v.z - b2f(h.z));
  h.w = f2b(v.w); l.w = f2b(v.w - b2f(h.w));
  ((ushort4*)xh)[i] = h;
  ((ushort4*)xl)[i] = l;
}

// ---------- transpose W[k][n] -> WT[n][k] bf16 (optionally hi/lo split) ----------
template <bool SPLIT>
__global__ __launch_bounds__(256) void transpose_kernel(const float* __restrict__ W,
                                                        u16* __restrict__ WhT,
                                                        u16* __restrict__ WlT) {
  __shared__ float tile[32][33];
  int tx = threadIdx.x & 31, ty = threadIdx.x >> 5;
  int n0 = blockIdx.x * 32, k0 = blockIdx.y * 32;
#pragma unroll
  for (int i = 0; i < 4; ++i)
    tile[ty + i * 8][tx] = W[(size_t)(k0 + ty + i * 8) * 2048 + n0 + tx];
  __syncthreads();
#pragma unroll
  for (int i = 0; i < 4; ++i) {
    int n = ty + i * 8;
    float v = tile[tx][n];
    u16 hv = f2b(v);
    WhT[(size_t)(n0 + n) * 2048 + k0 + tx] = hv;
    if constexpr (SPLIT)
      WlT[(size_t)(n0 + n) * 2048 + k0 + tx] = f2b(v - b2f(hv));
  }
}

// ---------- GEMM: C[4096][2048] = A[4096][2048] @ B^T[2048][2048] (+bias)*scale ----------
// SPLIT: A=Ah+Al, B=Bh+Bl, acc = Ah*Bh + Ah*Bl + Al*Bh (drops l*l, ~fp32 accurate)
// OUT_MODE: 0 = fp32 row-major, 1 = bf16 row-major, 2 = bf16 transposed to [b,h,d,s]
template <bool SPLIT, int OUT_MODE>
__global__ __launch_bounds__(256) void gemm_kernel(
    const u16* __restrict__ Ah, const u16* __restrict__ Al,
    const u16* __restrict__ Bh, const u16* __restrict__ Bl,
    const float* __restrict__ bias, float scale,
    float* __restrict__ Cf, u16* __restrict__ Cb) {
  __shared__ __align__(16) u16 smem[SPLIT ? 16384 : 8192];
  u16* sAh = smem;
  u16* sBh = smem + 4096;
  u16* sAl = smem + 8192;   // used only if SPLIT
  u16* sBl = smem + 12288;  // used only if SPLIT
  const int t = threadIdx.x;
  const int lane = t & 63, w = t >> 6;
  const int wr = w >> 1, wc = w & 1;
  const int quad = lane >> 4, l16 = lane & 15;
  const int m0 = blockIdx.y * 128, n0 = blockIdx.x * 128;

  f32x4 acc[4][4] = {};

  for (int kt = 0; kt < 64; ++kt) {  // K = 2048 / BK(32)
#pragma unroll
    for (int j = 0; j < 2; ++j) {
      int c = t + 256 * j;           // 512 chunks of 16B per 128x32 tile
      int row = c >> 2, cw = c & 3;
      size_t goff = (size_t)row * 2048 + kt * 32 + cw * 8;
      gload16(Ah + (size_t)m0 * 2048 + goff, (char*)sAh + c * 16);
      gload16(Bh + (size_t)n0 * 2048 + goff, (char*)sBh + c * 16);
      if constexpr (SPLIT) {
        gload16(Al + (size_t)m0 * 2048 + goff, (char*)sAl + c * 16);
        gload16(Bl + (size_t)n0 * 2048 + goff, (char*)sBl + c * 16);
      }
    }
    __syncthreads();
    bf16x8 ah[4], bh[4], al[4], bl[4];
#pragma unroll
    for (int i = 0; i < 4; ++i) {
      int ar = (wr * 64 + i * 16 + l16) * 32 + quad * 8;
      int br = (wc * 64 + i * 16 + l16) * 32 + quad * 8;
      ah[i] = *(const bf16x8*)&sAh[ar];
      bh[i] = *(const bf16x8*)&sBh[br];
      if constexpr (SPLIT) {
        al[i] = *(const bf16x8*)&sAl[ar];
        bl[i] = *(const bf16x8*)&sBl[br];
      }
    }
#pragma unroll
    for (int mi = 0; mi < 4; ++mi)
#pragma unroll
      for (int ni = 0; ni < 4; ++ni) {
        acc[mi][ni] = mfma_bf16(ah[mi], bh[ni], acc[mi][ni]);
        if constexpr (SPLIT) {
          acc[mi][ni] = mfma_bf16(ah[mi], bl[ni], acc[mi][ni]);
          acc[mi][ni] = mfma_bf16(al[mi], bh[ni], acc[mi][ni]);
        }
      }
    __syncthreads();
  }

#pragma unroll
  for (int mi = 0; mi < 4; ++mi) {
    int rowb = m0 + wr * 64 + mi * 16 + quad * 4;
#pragma unroll
    for (int ni = 0; ni < 4; ++ni) {
      int col = n0 + wc * 64 + ni * 16 + l16;
      float bv = bias[col];
#pragma unroll
      for (int r = 0; r < 4; ++r) {
        float v = (acc[mi][ni][r] + bv) * scale;
        int row = rowb + r;
        if constexpr (OUT_MODE == 0) {
          Cf[(size_t)row * 2048 + col] = v;
        } else if constexpr (OUT_MODE == 1) {
          Cb[(size_t)row * 2048 + col] = f2b(v);
        } else {
          // V transposed: [b][h][d][s], b=row>>11, s=row&2047, h=col>>7, d=col&127
          int b_ = row >> 11, s_ = row & 2047, h_ = col >> 7, d_ = col & 127;
          Cb[((size_t)((b_ * 16 + h_) * 128 + d_) << 11) + s_] = f2b(v);
        }
      }
    }
  }
}

// ---------- flash attention: Bq=64 (1 block), Bk=32 per iter, online softmax ----------
// Q,K fp32 (split to hi/lo bf16 in LDS for 3-MFMA exact-ish QK^T), V bf16 in [b,h,d,s]
__global__ __launch_bounds__(256) void attn_kernel(
    const float* __restrict__ Q, const float* __restrict__ K,
    const u16* __restrict__ VT, const float* __restrict__ bias,
    u16* __restrict__ ctx) {
  __shared__ __align__(16) u16 sm[31744];  // 62 KB
  u16* sQh = sm;          // [64][128]
  u16* sQl = sm + 8192;   // [64][128]
  u16* sKh = sm + 16384;  // [32][128]
  u16* sKl = sm + 20480;  // [32][128]
  u16* sVT = sm + 24576;  // [128][40] (32 data + pad, keeps 16B align, 2-way banks)
  u16* sP  = sm + 29696;  // [64][32]

  const int t = threadIdx.x, lane = t & 63, w = t >> 6;
  const int quad = lane >> 4, l16 = lane & 15;
  const int bh = blockIdx.y, b = bh >> 4, h = bh & 15;
  const int q0 = blockIdx.x * 64;

  // load + split Q tile (once)
  const size_t qbase = ((size_t)(b * 2048 + q0)) * 2048 + h * 128;
#pragma unroll 4
  for (int i = 0; i < 32; ++i) {
    int e = i * 256 + t;
    int row = e >> 7, col = e & 127;
    float v = Q[qbase + (size_t)row * 2048 + col];
    u16 hv = f2b(v);
    sQh[e] = hv;
    sQl[e] = f2b(v - b2f(hv));
  }

  f32x4 o[8] = {};
  float m_i[4] = {-3e38f, -3e38f, -3e38f, -3e38f};
  float l_i[4] = {0.f, 0.f, 0.f, 0.f};

  const size_t kbase = ((size_t)b * 2048) * 2048 + h * 128;
  const size_t vbase = ((size_t)bh * 128) * 2048;
  const float* biasp = bias + ((size_t)bh * 2048 + q0) * 2048;

  for (int kt = 0; kt < 64; ++kt) {
    int s0 = kt * 32;
    __syncthreads();  // all waves done reading previous K/V tiles
    // stage K tile, split hi/lo
#pragma unroll 4
    for (int i = 0; i < 16; ++i) {
      int e = i * 256 + t;
      int row = e >> 7, col = e & 127;
      float v = K[kbase + (size_t)(s0 + row) * 2048 + col];
      u16 hv = f2b(v);
      sKh[e] = hv;
      sKl[e] = f2b(v - b2f(hv));
    }
    // stage V^T tile: 128 d-rows x 32 s (padded stride 40)
#pragma unroll
    for (int j = 0; j < 4; ++j) {
      int c = t + 256 * j;  // 1024 chunks of 4 u16
      int d = c >> 3, sc = c & 7;
      ushort4 v4 = *(const ushort4*)(VT + vbase + (size_t)d * 2048 + s0 + sc * 4);
      *(ushort4*)&sVT[d * 40 + sc * 4] = v4;
    }
    __syncthreads();

    // QK^T: each wave does 16 q-rows x 32 s-cols; split 3-MFMA for accuracy
    f32x4 sc2[2] = {};
#pragma unroll
    for (int ks = 0; ks < 4; ++ks) {
      int qoff = (w * 16 + l16) * 128 + ks * 32 + quad * 8;
      bf16x8 qh = *(const bf16x8*)&sQh[qoff];
      bf16x8 ql = *(const bf16x8*)&sQl[qoff];
#pragma unroll
      for (int ni = 0; ni < 2; ++ni) {
        int koff = (ni * 16 + l16) * 128 + ks * 32 + quad * 8;
        bf16x8 kh = *(const bf16x8*)&sKh[koff];
        bf16x8 kl = *(const bf16x8*)&sKl[koff];
        sc2[ni] = mfma_bf16(qh, kh, sc2[ni]);
        sc2[ni] = mfma_bf16(qh, kl, sc2[ni]);
        sc2[ni] = mfma_bf16(ql, kh, sc2[ni]);
      }
    }

    // bias + online softmax (fp32). C-frag row = quad*4+r, col = l16 (+16*ni)
#pragma unroll
    for (int r = 0; r < 4; ++r) {
      int qrow = w * 16 + quad * 4 + r;
      float x0 = sc2[0][r] + biasp[(size_t)qrow * 2048 + s0 + l16];
      float x1 = sc2[1][r] + biasp[(size_t)qrow * 2048 + s0 + 16 + l16];
      float mx = fmaxf(x0, x1);
#pragma unroll
      for (int off = 1; off < 16; off <<= 1) mx = fmaxf(mx, __shfl_xor(mx, off));
      float mnew = fmaxf(m_i[r], mx);
      float alpha = exp2f((m_i[r] - mnew) * LOG2E);  // first iter: l=o=0, any alpha ok
      float p0 = exp2f((x0 - mnew) * LOG2E);
      float p1 = exp2f((x1 - mnew) * LOG2E);
      float sum = p0 + p1;
#pragma unroll
      for (int off = 1; off < 16; off <<= 1) sum += __shfl_xor(sum, off);
      l_i[r] = l_i[r] * alpha + sum;
      m_i[r] = mnew;
#pragma unroll
      for (int ni = 0; ni < 8; ++ni) o[ni][r] *= alpha;
      sP[qrow * 32 + l16] = f2b(p0);
      sP[qrow * 32 + 16 + l16] = f2b(p1);
    }

    // PV: A=P[16 q][32 s] (wave-local rows of sP), B=V^T[d][s]
    bf16x8 ap = *(const bf16x8*)&sP[(w * 16 + l16) * 32 + quad * 8];
#pragma unroll
    for (int ni = 0; ni < 8; ++ni) {
      bf16x8 bv = *(const bf16x8*)&sVT[(ni * 16 + l16) * 40 + quad * 8];
      o[ni] = mfma_bf16(ap, bv, o[ni]);
    }
  }

  float inv[4];
#pragma unroll
  for (int r = 0; r < 4; ++r) inv[r] = 1.f / l_i[r];
#pragma unroll
  for (int ni = 0; ni < 8; ++ni) {
#pragma unroll
    for (int r = 0; r < 4; ++r) {
      int qrow = w * 16 + quad * 4 + r;
      ctx[((size_t)(b * 2048 + q0 + qrow)) * 2048 + h * 128 + ni * 16 + l16] =
          f2b(o[ni][r] * inv[r]);
    }
  }
}

extern "C" void kernel_launch(void* const* d_in, const int* in_sizes, int n_in,
                              void* d_out, int out_size, void* d_ws, size_t ws_size,
                              hipStream_t stream) {
  (void)in_sizes; (void)n_in; (void)out_size; (void)ws_size;
  const float* x  = (const float*)d_in[0];
  const float* ab = (const float*)d_in[1];
  const float* Wq = (const float*)d_in[2];
  const float* bq = (const float*)d_in[3];
  const float* Wk = (const float*)d_in[4];
  const float* bk = (const float*)d_in[5];
  const float* Wv = (const float*)d_in[6];
  const float* bv = (const float*)d_in[7];
  const float* Wo = (const float*)d_in[8];
  const float* bo = (const float*)d_in[9];
  float* out = (float*)d_out;

  char* ws = (char*)d_ws;
  float* Kb  = (float*)(ws + 0);          // 33.5 MB fp32 K
  u16*   VT  = (u16*)(ws + 33554432);     // 16.8 MB bf16 V^T [b,h,d,s]
  u16*   ctx = (u16*)(ws + 50331648);     // 16.8 MB bf16 ctx [m][hid]
  u16*   xh  = (u16*)(ws + 67108864);     // 16.8 MB
  u16*   xl  = (u16*)(ws + 83886080);     // 16.8 MB
  u16*   WhT = (u16*)(ws + 100663296);    // 8.4 MB (reused per projection)
  u16*   WlT = (u16*)(ws + 109051904);    // 8.4 MB
  float* Qb  = out;                       // park Q in d_out (overwritten by final GEMM)

  const float SCALE = 11.313708499f;  // sqrt(128), multiplies q (faithful to reference)

  split_kernel<<<8192, 256, 0, stream>>>(x, xh, xl);

  transpose_kernel<true><<<dim3(64, 64), 256, 0, stream>>>(Wq, WhT, WlT);
  gemm_kernel<true, 0><<<dim3(16, 32), 256, 0, stream>>>(xh, xl, WhT, WlT, bq, SCALE, Qb, nullptr);

  transpose_kernel<true><<<dim3(64, 64), 256, 0, stream>>>(Wk, WhT, WlT);
  gemm_kernel<true, 0><<<dim3(16, 32), 256, 0, stream>>>(xh, xl, WhT, WlT, bk, 1.0f, Kb, nullptr);

  transpose_kernel<false><<<dim3(64, 64), 256, 0, stream>>>(Wv, WhT, nullptr);
  gemm_kernel<false, 2><<<dim3(16, 32), 256, 0, stream>>>(xh, nullptr, WhT, nullptr, bv, 1.0f, nullptr, VT);

  attn_kernel<<<dim3(32, 32), 256, 0, stream>>>(Qb, Kb, VT, ab, ctx);

  transpose_kernel<false><<<dim3(64, 64), 256, 0, stream>>>(Wo, WhT, nullptr);
  gemm_kernel<false, 0><<<dim3(16, 32), 256, 0, stream>>>(ctx, nullptr, WhT, nullptr, bo, 1.0f, out, nullptr);
}